// Round 17
// baseline (284.107 us; speedup 1.0000x reference)
//
#include <hip/hip_runtime.h>
#include <hip/hip_bf16.h>

// Problem constants
#define P 7
#define C_IN 512
#define C_MID 1024          // 2 * C_IN
#define C_CLS 1029          // P*P*21
#define C_BOX 4116          // P*P*21*4
#define FH 38
#define FW 50
#define NPIX 1900           // FH*FW
#define KROIS 300
#define COUT_SCORE 21
#define COUT_BOX 84
#define COUT_ALL 105

// Padded GEMM dims (multiples of 128)
#define MP1 1024
#define MPC 5248            // combined score+bbox, bin-major permuted (41*128)
#define MC_REAL 5145        // 49 * 105
#define NPAD 1920

// Static device scratch. Fully overwritten every call; deterministic.
__device__ unsigned short g_w1h[MP1 * C_IN],  g_w1l[MP1 * C_IN];      // w_double planes
__device__ unsigned short g_wch[MPC * C_MID], g_wcl[MPC * C_MID];     // combined permuted weights
__device__ float          g_biasc[MPC];                               // combined permuted bias
__device__ unsigned short g_fTh[NPAD * C_IN],  g_fTl[NPAD * C_IN];    // feature^T planes
__device__ unsigned short g_f2Th[NPAD * C_MID], g_f2Tl[NPAD * C_MID]; // feat2^T planes
__device__ float g_mapsT[(size_t)NPAD * MPC];                         // [pixel][b*105+c] f32

typedef __attribute__((ext_vector_type(8))) short bf16x8;
typedef __attribute__((ext_vector_type(4))) float f32x4;

// f32 -> bf16 (RTNE) on raw bits; values finite.
__device__ __forceinline__ unsigned short f2b(float x) {
    unsigned u = __float_as_uint(x);
    unsigned r = u + 0x7fffu + ((u >> 16) & 1u);
    return (unsigned short)(r >> 16);
}
__device__ __forceinline__ float b2f(unsigned short h) {
    return __uint_as_float((unsigned)h << 16);
}

// async global->LDS, 16B per lane. LDS dest = uniform base + lane*16 (HW).
#define GLOAD16(gp, lp)                                                        \
    __builtin_amdgcn_global_load_lds(                                          \
        (const __attribute__((address_space(1))) void*)(gp),                   \
        (__attribute__((address_space(3))) void*)(lp), 16, 0, 0)

// ---------------------------------------------------------------------------
// Split f32 array into bf16 hi/lo planes, zero-padding tail rows.
// ---------------------------------------------------------------------------
__global__ __launch_bounds__(256) void split_pad_k(
    const float* __restrict__ src,
    unsigned short* __restrict__ h, unsigned short* __restrict__ l,
    int n_in4, int n_pad4)
{
    const int i = blockIdx.x * 256 + threadIdx.x;
    if (i >= n_pad4) return;
    float4 v = make_float4(0.f, 0.f, 0.f, 0.f);
    if (i < n_in4) v = reinterpret_cast<const float4*>(src)[i];
    ushort4 hh, lv;
    hh.x = f2b(v.x); lv.x = f2b(v.x - b2f(hh.x));
    hh.y = f2b(v.y); lv.y = f2b(v.y - b2f(hh.y));
    hh.z = f2b(v.z); lv.z = f2b(v.z - b2f(hh.z));
    hh.w = f2b(v.w); lv.w = f2b(v.w - b2f(hh.w));
    reinterpret_cast<ushort4*>(h)[i] = hh;
    reinterpret_cast<ushort4*>(l)[i] = lv;
}

// ---------------------------------------------------------------------------
// Combined, bin-major-permuted weight split:
//   row m = b*105 + c  <-  w_score[c*49+b] (c<21) | w_bbox[(c-21)*49+b]
// Also emits the permuted bias. Rows >= 5145 zero.
// One thread per 8 k-elements.
// ---------------------------------------------------------------------------
__global__ __launch_bounds__(256) void permute_split_k(
    const float* __restrict__ ws, const float* __restrict__ wb,
    const float* __restrict__ bs, const float* __restrict__ bb,
    unsigned short* __restrict__ h, unsigned short* __restrict__ l,
    float* __restrict__ biasp)
{
    const int idx = blockIdx.x * 256 + threadIdx.x;   // MPC * (C_MID/8) total
    const int m = idx >> 7;            // / (C_MID/8 = 128)
    const int ko = (idx & 127) * 8;
    if (m >= MPC) return;
    float v[8] = {0.f, 0.f, 0.f, 0.f, 0.f, 0.f, 0.f, 0.f};
    float bv = 0.f;
    if (m < MC_REAL) {
        const int b = m / COUT_ALL, c = m % COUT_ALL;
        const float* src;
        if (c < COUT_SCORE) { const int r = c * 49 + b;                src = ws + (size_t)r * C_MID; bv = bs[r]; }
        else                { const int r = (c - COUT_SCORE) * 49 + b; src = wb + (size_t)r * C_MID; bv = bb[r]; }
        const float4 a0 = *reinterpret_cast<const float4*>(src + ko);
        const float4 a1 = *reinterpret_cast<const float4*>(src + ko + 4);
        v[0] = a0.x; v[1] = a0.y; v[2] = a0.z; v[3] = a0.w;
        v[4] = a1.x; v[5] = a1.y; v[6] = a1.z; v[7] = a1.w;
    }
    ushort4 hh0, hh1, lv0, lv1;
    unsigned short th[8], tl[8];
    #pragma unroll
    for (int q = 0; q < 8; ++q) { th[q] = f2b(v[q]); tl[q] = f2b(v[q] - b2f(th[q])); }
    hh0 = make_ushort4(th[0], th[1], th[2], th[3]);
    hh1 = make_ushort4(th[4], th[5], th[6], th[7]);
    lv0 = make_ushort4(tl[0], tl[1], tl[2], tl[3]);
    lv1 = make_ushort4(tl[4], tl[5], tl[6], tl[7]);
    reinterpret_cast<ushort4*>(h + (size_t)m * C_MID + ko)[0] = hh0;
    reinterpret_cast<ushort4*>(h + (size_t)m * C_MID + ko)[1] = hh1;
    reinterpret_cast<ushort4*>(l + (size_t)m * C_MID + ko)[0] = lv0;
    reinterpret_cast<ushort4*>(l + (size_t)m * C_MID + ko)[1] = lv1;
    if (ko == 0) biasp[m] = bv;
}

// ---------------------------------------------------------------------------
// Transpose feature [512][1900] -> g_fTh/g_fTl bf16 [1920][512] (pad rows 0).
// ---------------------------------------------------------------------------
__global__ __launch_bounds__(256) void transpose_split_k(const float* __restrict__ in)
{
    __shared__ float t[32][33];
    const int n0 = blockIdx.x * 32;
    const int k0 = blockIdx.y * 32;
    const int tx = threadIdx.x & 31;
    const int ty = threadIdx.x >> 5;
    #pragma unroll
    for (int j = 0; j < 4; ++j) {
        const int kk = k0 + ty + j * 8;
        const int nn = n0 + tx;
        t[ty + j * 8][tx] = (nn < NPIX) ? in[kk * NPIX + nn] : 0.f;
    }
    __syncthreads();
    #pragma unroll
    for (int j = 0; j < 4; ++j) {
        const int nn = n0 + ty + j * 8;
        const int kk = k0 + tx;
        const float v = t[tx][ty + j * 8];
        const unsigned short hh = f2b(v);
        g_fTh[(size_t)nn * C_IN + kk] = hh;
        g_fTl[(size_t)nn * C_IN + kk] = f2b(v - b2f(hh));
    }
}

// ---------------------------------------------------------------------------
// Split-bf16 MFMA GEMM + bias + relu — 2-PHASE DOUBLE-BUFFERED (T3-minimum):
// BK=32, two 32KB LDS buffers; STAGE(next) issued BEFORE the MFMA burst,
// vmcnt(0) drained AFTER -> HBM latency hides under 48 MFMAs/wave/step.
// Accumulation order unchanged (k ascending) -> bitwise-identical numerics.
// XOR swizzle (4 x 16B slots per 64B row): logical k-seg s of row r stored
// at slot s^(r&3); staged via pre-swizzled GLOBAL source (linear LDS dest,
// rule-21-correct), read with the same XOR -> conflict-free.
//   OUT_MODE 0: f32 transposed out[n*M + m]   (mapsT for combined gemm)
//   OUT_MODE 1: bf16 hi/lo transposed planes  (feat2T for gemm1)
// ---------------------------------------------------------------------------
template <int OUT_MODE>
__global__ __launch_bounds__(256) void gemm_mfma(
    const unsigned short* __restrict__ Ah, const unsigned short* __restrict__ Al,
    const unsigned short* __restrict__ Bh, const unsigned short* __restrict__ Bl,
    const float* __restrict__ bias,
    float* __restrict__ outf,
    unsigned short* __restrict__ outh, unsigned short* __restrict__ outl,
    int M, int K)
{
    __shared__ unsigned char lds[65536];   // 2 bufs x {Ah,Al,Bh,Bl} x 8KB

    const int tid = threadIdx.x;
    const int bm = blockIdx.y * 128;
    const int bn = blockIdx.x * 128;
    const int lane = tid & 63;
    const int wid = tid >> 6;
    const int uwid = __builtin_amdgcn_readfirstlane(wid);
    const int wr = (wid >> 1) * 64;
    const int wc = (wid & 1) * 64;
    const int ll = lane & 15;
    const int lg = lane >> 4;        // 0..3 (k-seg)
    const int lh4 = lg * 4;

    // staging: wave uwid stages plane uwid (0=Ah 1=Al 2=Bh 3=Bl).
    // per instr g: 16 rows x 64B. lane -> row g*16 + (lane>>2), dest slot lane&3;
    // source k-seg = (lane&3) ^ (row&3)  (pre-swizzled global address).
    const int lrow = lane >> 2;                 // 0..15
    const int lseg = (lane & 3) ^ (lrow & 3);
    const unsigned short* gsrc = (uwid == 0) ? Ah : (uwid == 1) ? Al : (uwid == 2) ? Bh : Bl;
    const int rbase = (uwid < 2) ? bm : bn;
    const size_t grow = (size_t)(rbase + lrow) * K + lseg * 8;

    f32x4 acc[4][4];
    #pragma unroll
    for (int i = 0; i < 4; ++i)
        #pragma unroll
        for (int j = 0; j < 4; ++j) {
            f32x4 z = {0.f, 0.f, 0.f, 0.f};
            acc[i][j] = z;
        }

    auto STAGE = [&](int buf, int k0) {
        const unsigned short* gp = gsrc + grow + k0;
        unsigned char* lp = &lds[buf * 32768 + uwid * 8192];
        #pragma unroll
        for (int g = 0; g < 8; ++g)
            GLOAD16(gp + (size_t)g * 16 * K, lp + g * 1024);
    };

    STAGE(0, 0);
    asm volatile("s_waitcnt vmcnt(0)" ::: "memory");
    __syncthreads();

    int cur = 0;
    for (int k0 = 0; k0 < K; k0 += 32) {
        if (k0 + 32 < K) STAGE(cur ^ 1, k0 + 32);   // flies under the MFMAs

        const unsigned char* base = &lds[cur * 32768];
        const unsigned char* pAh = base;
        const unsigned char* pAl = base + 8192;
        const unsigned char* pBh = base + 16384;
        const unsigned char* pBl = base + 24576;

        bf16x8 bh[4], bl[4];
        #pragma unroll
        for (int nt = 0; nt < 4; ++nt) {
            const int r = wc + nt * 16 + ll;
            const int off = r * 64 + ((lg ^ (r & 3)) << 4);
            bh[nt] = *reinterpret_cast<const bf16x8*>(pBh + off);
            bl[nt] = *reinterpret_cast<const bf16x8*>(pBl + off);
        }
        #pragma unroll
        for (int mt = 0; mt < 4; ++mt) {
            const int r = wr + mt * 16 + ll;
            const int off = r * 64 + ((lg ^ (r & 3)) << 4);
            const bf16x8 ah = *reinterpret_cast<const bf16x8*>(pAh + off);
            const bf16x8 al = *reinterpret_cast<const bf16x8*>(pAl + off);
            #pragma unroll
            for (int nt = 0; nt < 4; ++nt) {
                acc[mt][nt] = __builtin_amdgcn_mfma_f32_16x16x32_bf16(ah, bh[nt], acc[mt][nt], 0, 0, 0);
                acc[mt][nt] = __builtin_amdgcn_mfma_f32_16x16x32_bf16(ah, bl[nt], acc[mt][nt], 0, 0, 0);
                acc[mt][nt] = __builtin_amdgcn_mfma_f32_16x16x32_bf16(al, bh[nt], acc[mt][nt], 0, 0, 0);
            }
        }
        asm volatile("s_waitcnt vmcnt(0)" ::: "memory");
        __syncthreads();
        cur ^= 1;
    }

    // ---- epilogue: bias + relu. C/D: col = lane&15, row = (lane>>4)*4+reg ----
    #pragma unroll
    for (int mt = 0; mt < 4; ++mt) {
        #pragma unroll
        for (int nt = 0; nt < 4; ++nt) {
            const int m0 = bm + wr + mt * 16 + lh4;
            const int n  = bn + wc + nt * 16 + ll;
            const float o0 = fmaxf(acc[mt][nt][0] + bias[m0 + 0], 0.f);
            const float o1 = fmaxf(acc[mt][nt][1] + bias[m0 + 1], 0.f);
            const float o2 = fmaxf(acc[mt][nt][2] + bias[m0 + 2], 0.f);
            const float o3 = fmaxf(acc[mt][nt][3] + bias[m0 + 3], 0.f);
            if (OUT_MODE == 0) {
                float4 o = make_float4(o0, o1, o2, o3);
                *reinterpret_cast<float4*>(&outf[(size_t)n * M + m0]) = o;
            } else {
                ushort4 hh, lv;
                hh.x = f2b(o0); lv.x = f2b(o0 - b2f(hh.x));
                hh.y = f2b(o1); lv.y = f2b(o1 - b2f(hh.y));
                hh.z = f2b(o2); lv.z = f2b(o2 - b2f(hh.z));
                hh.w = f2b(o3); lv.w = f2b(o3 - b2f(hh.w));
                *reinterpret_cast<ushort4*>(&outh[(size_t)n * M + m0]) = hh;
                *reinterpret_cast<ushort4*>(&outl[(size_t)n * M + m0]) = lv;
            }
        }
    }
}

// ---------------------------------------------------------------------------
// PS-ROI pool + bin-mean, COALESCED via bin-major mapsT[pixel][b*105+c].
// SEMANTICS LOCKED (R14-verified): strict-f32 roi prep, bin via
// rn32(roi * rn32(1/7)), mul-then-add RN boundaries, clipped cnt.
// Thread = output channel c (128 lanes, c<105 active); 2 rois per block.
// Bin loop b = 0..48 ascending and pixel order y-major/x-inner are IDENTICAL
// to the verified kernel -> identical f32 accumulation order.
// ---------------------------------------------------------------------------
__global__ __launch_bounds__(256) void psroi_pool_mean(
    const float* __restrict__ rois, const float* __restrict__ mapsT,
    float* __restrict__ out)
{
    const int half = threadIdx.x >> 7;        // 0/1
    const int c = threadIdx.x & 127;          // channel lane
    const int k = blockIdx.x * 2 + half;      // roi, grid exact (150*2=300)

    // rois layout: (ymin, xmin, ymax, xmax); reference permutes to xyxy.
    const float ymin = rois[k * 4 + 0];
    const float xmin = rois[k * 4 + 1];
    const float ymax = rois[k * 4 + 2];
    const float xmax = rois[k * 4 + 3];

    const float x1 = __fmul_rn(rintf(xmin), 0.0625f);
    const float y1 = __fmul_rn(rintf(ymin), 0.0625f);
    const float x2 = __fmul_rn(__fadd_rn(rintf(xmax), 1.0f), 0.0625f);
    const float y2 = __fmul_rn(__fadd_rn(rintf(ymax), 1.0f), 0.0625f);
    const float roi_w = fmaxf(__fsub_rn(x2, x1), 0.1f);
    const float roi_h = fmaxf(__fsub_rn(y2, y1), 0.1f);
    const float inv7 = 1.0f / 7.0f;   // constant-folded rn32(1/7)
    const float bin_w = __fmul_rn(roi_w, inv7);
    const float bin_h = __fmul_rn(roi_h, inv7);

    float tot = 0.f;
    for (int b = 0; b < 49; ++b) {
        const int i = b / 7;
        const int j = b % 7;
        const float hs = fminf(fmaxf(floorf(__fadd_rn(y1, __fmul_rn(bin_h, (float)i))), 0.f), (float)FH);
        const float he = fminf(fmaxf(ceilf (__fadd_rn(y1, __fmul_rn(bin_h, (float)(i + 1)))), 0.f), (float)FH);
        const float wsb = fminf(fmaxf(floorf(__fadd_rn(x1, __fmul_rn(bin_w, (float)j))), 0.f), (float)FW);
        const float web = fminf(fmaxf(ceilf (__fadd_rn(x1, __fmul_rn(bin_w, (float)(j + 1)))), 0.f), (float)FW);
        const float cnt = __fmul_rn(__fsub_rn(he, hs), __fsub_rn(web, wsb));
        float val = 0.f;
        if (cnt > 0.f) {
            const int ys = (int)hs, ye = (int)he, xs = (int)wsb, xe = (int)web;
            const float* mb = mapsT + (size_t)b * COUT_ALL + c;   // column base
            float s = 0.f;
            for (int y = ys; y < ye; ++y)
                for (int x = xs; x < xe; ++x)
                    s += mb[(size_t)(y * FW + x) * MPC];          // coalesced over c
            val = s / fmaxf(cnt, 1.0f);
        }
        tot += val;
    }

    if (c < COUT_ALL) {
        const float r = tot * (1.0f / 49.0f);
        if (c < COUT_SCORE) out[(size_t)k * COUT_SCORE + c] = r;
        else out[(size_t)KROIS * COUT_SCORE + (size_t)k * COUT_BOX + (c - COUT_SCORE)] = r;
    }
}

extern "C" void kernel_launch(void* const* d_in, const int* in_sizes, int n_in,
                              void* d_out, int out_size, void* d_ws, size_t ws_size,
                              hipStream_t stream) {
    const float* feature  = (const float*)d_in[0];   // [512, 38, 50]
    const float* rois     = (const float*)d_in[1];   // [300, 4]
    const float* w_double = (const float*)d_in[2];   // [1024, 512]
    const float* b_double = (const float*)d_in[3];   // [1024]
    const float* w_score  = (const float*)d_in[4];   // [1029, 1024]
    const float* b_score  = (const float*)d_in[5];   // [1029]
    const float* w_bbox   = (const float*)d_in[6];   // [4116, 1024]
    const float* b_bbox   = (const float*)d_in[7];   // [4116]
    float* out = (float*)d_out;                       // 6300 + 25200 floats

    unsigned short *w1h, *w1l, *wch, *wcl, *fTh, *fTl, *f2Th, *f2Tl;
    float *biasc, *mapsT;
    hipGetSymbolAddress((void**)&w1h,   HIP_SYMBOL(g_w1h));
    hipGetSymbolAddress((void**)&w1l,   HIP_SYMBOL(g_w1l));
    hipGetSymbolAddress((void**)&wch,   HIP_SYMBOL(g_wch));
    hipGetSymbolAddress((void**)&wcl,   HIP_SYMBOL(g_wcl));
    hipGetSymbolAddress((void**)&biasc, HIP_SYMBOL(g_biasc));
    hipGetSymbolAddress((void**)&fTh,   HIP_SYMBOL(g_fTh));
    hipGetSymbolAddress((void**)&fTl,   HIP_SYMBOL(g_fTl));
    hipGetSymbolAddress((void**)&f2Th,  HIP_SYMBOL(g_f2Th));
    hipGetSymbolAddress((void**)&f2Tl,  HIP_SYMBOL(g_f2Tl));
    hipGetSymbolAddress((void**)&mapsT, HIP_SYMBOL(g_mapsT));

    const dim3 blk(256);

    // w_double -> bf16 hi/lo planes (1024 rows exact, no pad)
    split_pad_k<<<(MP1 * C_IN / 4 + 255) / 256, blk, 0, stream>>>(
        w_double, w1h, w1l, C_MID * C_IN / 4, MP1 * C_IN / 4);

    // combined permuted weights + bias (score|bbox, bin-major rows)
    permute_split_k<<<(MPC * (C_MID / 8) + 255) / 256, blk, 0, stream>>>(
        w_score, w_bbox, b_score, b_bbox, wch, wcl, biasc);

    // feature [512][1900] -> fT hi/lo [1920][512]
    transpose_split_k<<<dim3(NPAD / 32, C_IN / 32), blk, 0, stream>>>(feature);

    // gemm1: feat2T hi/lo planes (transposed bf16 epilogue)
    gemm_mfma<1><<<dim3(NPAD / 128, MP1 / 128), blk, 0, stream>>>(
        w1h, w1l, fTh, fTl, b_double, nullptr, f2Th, f2Tl, MP1, C_IN);

    // combined gemm: mapsT[pixel][b*105+c] f32 (transposed epilogue)
    gemm_mfma<0><<<dim3(NPAD / 128, MPC / 128), blk, 0, stream>>>(
        wch, wcl, f2Th, f2Tl, biasc, mapsT, nullptr, nullptr, MPC, C_MID);

    // coalesced pool
    psroi_pool_mean<<<dim3(KROIS / 2), blk, 0, stream>>>(rois, mapsT, out);
}